// Round 2
// baseline (549.167 us; speedup 1.0000x reference)
//
#include <hip/hip_runtime.h>

#define B_TOT 65536
#define SEQ   32

typedef __bf16 bf16_8 __attribute__((ext_vector_type(8)));
typedef float  float4v __attribute__((ext_vector_type(4)));

__device__ inline float bf2f(unsigned short s){
    unsigned u = ((unsigned)s) << 16;
    return __builtin_bit_cast(float, u);
}
__device__ inline unsigned short f2bf(float f){
    unsigned u = __builtin_bit_cast(unsigned, f);
    u += 0x7FFFu + ((u >> 16) & 1u);           // round-to-nearest-even
    return (unsigned short)(u >> 16);
}
__device__ inline float fsig(float x){        // sigmoid via exp2
    float e = __builtin_amdgcn_exp2f(-1.4426950408889634f * x);
    return __builtin_amdgcn_rcpf(1.0f + e);
}
__device__ inline float ftanh(float x){       // tanh = 2*sigmoid(2x)-1
    float e = __builtin_amdgcn_exp2f(-2.8853900817779268f * x);
    return 2.0f * __builtin_amdgcn_rcpf(1.0f + e) - 1.0f;
}

// ---- prep: W_eff = w_hh.T + w_pos.T @ (w_emb.T @ w_ih.T); biases folded ----
// All inputs fp32. Emits bf16 W_eff (512,128), fp32 beff (512), fp32 m2 (2,512),
// bf16 copy of w_pos (2,128).
__global__ void prep_kernel(const float* __restrict__ w_ih,
                            const float* __restrict__ w_hh,
                            const float* __restrict__ b_ih,
                            const float* __restrict__ b_hh,
                            const float* __restrict__ w_emb,
                            const float* __restrict__ b_emb,
                            const float* __restrict__ w_pos,
                            const float* __restrict__ b_pos,
                            unsigned short* __restrict__ weff,
                            float* __restrict__ beff,
                            float* __restrict__ m2,
                            unsigned short* __restrict__ wposb)
{
    int n = threadIdx.x;                       // 512 threads, one gate col each
    float m20 = 0.f, m21 = 0.f, bi = 0.f;
    for (int e = 0; e < 64; ++e){
        float wv = w_ih[n*64 + e];
        m20 += w_emb[e*2 + 0] * wv;
        m21 += w_emb[e*2 + 1] * wv;
        bi  += b_emb[e] * wv;
    }
    m2[n]       = m20;
    m2[512 + n] = m21;
    beff[n] = b_ih[n] + b_hh[n] + bi + b_pos[0]*m20 + b_pos[1]*m21;
    for (int k = 0; k < 128; ++k){
        float wv = w_hh[n*128 + k] + w_pos[k]*m20 + w_pos[128 + k]*m21;
        weff[n*128 + k] = f2bf(wv);
    }
    if (n < 256) wposb[n] = f2bf(w_pos[n]);
}

// ---- main decoder: 16 rows/block, 4 waves; W_eff b-frags resident in VGPRs ----
__global__ __launch_bounds__(256, 2) void dec_kernel(
    const float* __restrict__ lpr,             // (B,2) last_pos_rel fp32
    const float* __restrict__ hh,              // (B,128) fp32
    const float* __restrict__ ch,              // (B,128) fp32
    const float* __restrict__ b_pos,           // (2) fp32
    const unsigned short* __restrict__ wposb,  // (2,128) bf16
    const unsigned short* __restrict__ weff,   // (512,128) bf16
    const float* __restrict__ beff,            // (512) fp32
    const float* __restrict__ m2,              // (2,512) fp32
    float* __restrict__ out)                   // rels (32,B,2) ++ h (B,128) fp32
{
    __shared__ __align__(16) unsigned short lh[2][16][136];  // h double buffer (+pad)
    __shared__ float ubuf[16][2];

    const int tid  = threadIdx.x;
    const int w    = tid >> 6;
    const int lane = tid & 63;
    const int q    = lane >> 4;
    const int l    = lane & 15;
    const int row0 = blockIdx.x << 4;

    // stage h0 -> lh[0], c0 -> lh[1]: fp32 global, converted to bf16 in LDS
    {
        int r = tid >> 4, c8 = (tid & 15) << 3;
        const float* ph = hh + ((row0 + r) << 7) + c8;
        const float* pc = ch + ((row0 + r) << 7) + c8;
        float4 h0v = *(const float4*)ph, h1v = *(const float4*)(ph + 4);
        float4 c0v = *(const float4*)pc, c1v = *(const float4*)(pc + 4);
        unsigned short hb[8], cb[8];
        hb[0]=f2bf(h0v.x); hb[1]=f2bf(h0v.y); hb[2]=f2bf(h0v.z); hb[3]=f2bf(h0v.w);
        hb[4]=f2bf(h1v.x); hb[5]=f2bf(h1v.y); hb[6]=f2bf(h1v.z); hb[7]=f2bf(h1v.w);
        cb[0]=f2bf(c0v.x); cb[1]=f2bf(c0v.y); cb[2]=f2bf(c0v.z); cb[3]=f2bf(c0v.w);
        cb[4]=f2bf(c1v.x); cb[5]=f2bf(c1v.y); cb[6]=f2bf(c1v.z); cb[7]=f2bf(c1v.w);
        *(uint4*)&lh[0][r][c8] = *(const uint4*)hb;
        *(uint4*)&lh[1][r][c8] = *(const uint4*)cb;
    }
    __syncthreads();

    // c state in C-layout fp32 registers (initial c0 bf16-quantized; carried fp32 after)
    float c0r[4], c1r[4];
#pragma unroll
    for (int r4 = 0; r4 < 4; ++r4){
        c0r[r4] = bf2f(lh[1][q*4 + r4][32*w + l]);
        c1r[r4] = bf2f(lh[1][q*4 + r4][32*w + 16 + l]);
    }

    // A-frags of h0
    bf16_8 a[4];
#pragma unroll
    for (int kt = 0; kt < 4; ++kt)
        a[kt] = *(const bf16_8*)&lh[0][l][kt*32 + q*8];

    // resident W_eff b-frags + bias (loaded once, reused all 32 steps)
    bf16_8 bfr[8][4];
    float bias[8];
#pragma unroll
    for (int t8 = 0; t8 < 8; ++t8){
        int nb = ((t8 >> 1) << 7) + 32*w + ((t8 & 1) << 4) + l;
#pragma unroll
        for (int kt = 0; kt < 4; ++kt)
            bfr[t8][kt] = *(const bf16_8*)(weff + (nb << 7) + kt*32 + q*8);
        bias[t8] = beff[nb];
    }

    // w_pos b-frags (bf16 copy) for the rel MFMA; cols >=2 duplicate col 0
    bf16_8 wp[4];
    {
        int n2 = (l < 2) ? l : 0;
#pragma unroll
        for (int kt = 0; kt < 4; ++kt)
            wp[kt] = *(const bf16_8*)(wposb + (n2 << 7) + kt*32 + q*8);
    }
    float bposv = b_pos[l & 1];

    // wave0: r_{-1} = h0 @ w_pos.T + b_pos ; u0' = lpr - r_{-1}
    if (w == 0){
        float4v racc = {0.f, 0.f, 0.f, 0.f};
#pragma unroll
        for (int kt = 0; kt < 4; ++kt)
            racc = __builtin_amdgcn_mfma_f32_16x16x32_bf16(a[kt], wp[kt], racc, 0, 0, 0);
        if (l < 2){
#pragma unroll
            for (int r4 = 0; r4 < 4; ++r4){
                int row = q*4 + r4;
                float lp = lpr[((row0 + row) << 1) + l];
                ubuf[row][l] = lp - (racc[r4] + bposv);
            }
        }
    }
    __syncthreads();

    float4v acc[8];

    auto do_gates = [&](){
#pragma unroll
        for (int t8 = 0; t8 < 8; ++t8){
            float bb = bias[t8];
            acc[t8] = (float4v){bb, bb, bb, bb};
        }
#pragma unroll
        for (int kt = 0; kt < 4; ++kt)
#pragma unroll
            for (int t8 = 0; t8 < 8; ++t8)
                acc[t8] = __builtin_amdgcn_mfma_f32_16x16x32_bf16(a[kt], bfr[t8][kt], acc[t8], 0, 0, 0);
    };

    auto do_elem_write = [&](int buf, int final_h){
#pragma unroll
        for (int X = 0; X < 2; ++X){
#pragma unroll
            for (int r4 = 0; r4 < 4; ++r4){
                float ig = acc[0 + X][r4];
                float fg = acc[2 + X][r4];
                float gg = acc[4 + X][r4];
                float og = acc[6 + X][r4];
                float cold = X ? c1r[r4] : c0r[r4];
                float c2 = fsig(fg)*cold + fsig(ig)*ftanh(gg);
                float h2 = fsig(og)*ftanh(c2);
                if (X) c1r[r4] = c2; else c0r[r4] = c2;
                lh[buf][q*4 + r4][32*w + 16*X + l] = f2bf(h2);
                if (final_h)
                    out[SEQ*B_TOT*2 + ((row0 + q*4 + r4) << 7) + 32*w + 16*X + l] = h2;
            }
        }
    };

    auto reload_and_rel = [&](int buf, int t){
#pragma unroll
        for (int kt = 0; kt < 4; ++kt)
            a[kt] = *(const bf16_8*)&lh[buf][l][kt*32 + q*8];
        if (w == 0){
            float4v racc = {0.f, 0.f, 0.f, 0.f};
#pragma unroll
            for (int kt = 0; kt < 4; ++kt)
                racc = __builtin_amdgcn_mfma_f32_16x16x32_bf16(a[kt], wp[kt], racc, 0, 0, 0);
            if (l < 2){
#pragma unroll
                for (int r4 = 0; r4 < 4; ++r4)
                    out[t*(B_TOT*2) + ((row0 + q*4 + r4) << 1) + l] = racc[r4] + bposv;
            }
        }
    };

    // ---- step 0 (peeled: rank-2 input correction) ----
    do_gates();
    {
        float uu0[4], uu1[4];
#pragma unroll
        for (int r4 = 0; r4 < 4; ++r4){
            uu0[r4] = ubuf[q*4 + r4][0];
            uu1[r4] = ubuf[q*4 + r4][1];
        }
#pragma unroll
        for (int t8 = 0; t8 < 8; ++t8){
            int nb = ((t8 >> 1) << 7) + 32*w + ((t8 & 1) << 4) + l;
            float ma = m2[nb], mb = m2[512 + nb];
#pragma unroll
            for (int r4 = 0; r4 < 4; ++r4)
                acc[t8][r4] += uu0[r4]*ma + uu1[r4]*mb;
        }
    }
    do_elem_write(1, 0);
    __syncthreads();
    reload_and_rel(1, 0);

    // ---- steps 1..31 ----
    for (int t = 1; t < SEQ; ++t){
        do_gates();
        do_elem_write((t + 1) & 1, t == SEQ - 1);
        __syncthreads();
        reload_and_rel((t + 1) & 1, t);
    }
}

extern "C" void kernel_launch(void* const* d_in, const int* in_sizes, int n_in,
                              void* d_out, int out_size, void* d_ws, size_t ws_size,
                              hipStream_t stream)
{
    (void)in_sizes; (void)n_in; (void)out_size; (void)ws_size;

    const float* lpr   = (const float*)d_in[1];
    const float* hh    = (const float*)d_in[2];
    const float* ch    = (const float*)d_in[3];
    const float* w_ih  = (const float*)d_in[5];
    const float* w_hh  = (const float*)d_in[6];
    const float* b_ih  = (const float*)d_in[7];
    const float* b_hh  = (const float*)d_in[8];
    const float* w_emb = (const float*)d_in[9];
    const float* b_emb = (const float*)d_in[10];
    const float* w_pos = (const float*)d_in[11];
    const float* b_pos = (const float*)d_in[12];

    unsigned short* weff  = (unsigned short*)d_ws;                    // 512*128 bf16
    float* beff           = (float*)((char*)d_ws + 512*128*2);        // 512 f32
    float* m2             = (float*)((char*)d_ws + 512*128*2 + 2048); // 1024 f32
    unsigned short* wposb = (unsigned short*)((char*)d_ws + 512*128*2 + 2048 + 4096); // 256 bf16

    hipLaunchKernelGGL(prep_kernel, dim3(1), dim3(512), 0, stream,
                       w_ih, w_hh, b_ih, b_hh, w_emb, b_emb, w_pos, b_pos,
                       weff, beff, m2, wposb);
    hipLaunchKernelGGL(dec_kernel, dim3(B_TOT/16), dim3(256), 0, stream,
                       lpr, hh, ch, b_pos, wposb, weff, beff, m2,
                       (float*)d_out);
}

// Round 3
// 545.475 us; speedup vs baseline: 1.0068x; 1.0068x over previous
//
#include <hip/hip_runtime.h>

#define B_TOT 65536
#define SEQ   32

typedef __bf16 bf16_8 __attribute__((ext_vector_type(8)));
typedef __bf16 bf16_4 __attribute__((ext_vector_type(4)));
typedef float  float4v __attribute__((ext_vector_type(4)));
typedef float  float2v __attribute__((ext_vector_type(2)));

__device__ inline unsigned short f2bf(float f){
    unsigned u = __builtin_bit_cast(unsigned, f);
    u += 0x7FFFu + ((u >> 16) & 1u);           // round-to-nearest-even
    return (unsigned short)(u >> 16);
}
__device__ inline float fsig(float x){        // sigmoid via exp2
    float e = __builtin_amdgcn_exp2f(-1.4426950408889634f * x);
    return __builtin_amdgcn_rcpf(1.0f + e);
}
__device__ inline float ftanh(float x){       // tanh = 2*sigmoid(2x)-1
    float e = __builtin_amdgcn_exp2f(-2.8853900817779268f * x);
    return 2.0f * __builtin_amdgcn_rcpf(1.0f + e) - 1.0f;
}

// ---- prep: W_eff = w_hh.T + w_pos.T @ (w_emb.T @ w_ih.T); biases folded ----
// Emits bf16 W_eff (512,128), fp32 beff (512), fp32 m2 (2,512),
// bf16 wposA (16,128): rows 0,1 = w_pos, rows 2..15 = 0 (safe A-frag source).
__global__ void prep_kernel(const float* __restrict__ w_ih,
                            const float* __restrict__ w_hh,
                            const float* __restrict__ b_ih,
                            const float* __restrict__ b_hh,
                            const float* __restrict__ w_emb,
                            const float* __restrict__ b_emb,
                            const float* __restrict__ w_pos,
                            const float* __restrict__ b_pos,
                            unsigned short* __restrict__ weff,
                            float* __restrict__ beff,
                            float* __restrict__ m2,
                            unsigned short* __restrict__ wposA)
{
    int n = threadIdx.x;                       // 512 threads, one gate col each
    float m20 = 0.f, m21 = 0.f, bi = 0.f;
    for (int e = 0; e < 64; ++e){
        float wv = w_ih[n*64 + e];
        m20 += w_emb[e*2 + 0] * wv;
        m21 += w_emb[e*2 + 1] * wv;
        bi  += b_emb[e] * wv;
    }
    m2[n]       = m20;
    m2[512 + n] = m21;
    beff[n] = b_ih[n] + b_hh[n] + bi + b_pos[0]*m20 + b_pos[1]*m21;
    for (int k = 0; k < 128; ++k){
        float wv = w_hh[n*128 + k] + w_pos[k]*m20 + w_pos[128 + k]*m21;
        weff[n*128 + k] = f2bf(wv);
    }
    if (n < 256) wposA[n] = f2bf(w_pos[n]);
    for (int idx = n; idx < 14*128; idx += 512) wposA[256 + idx] = 0;
}

// ---- main decoder: G^T = W_eff(A) x h^T(B); 16 rows/block, 4 waves ----
__global__ __launch_bounds__(256, 2) void dec_kernel(
    const float* __restrict__ lpr,             // (B,2)
    const float* __restrict__ hh,              // (B,128)
    const float* __restrict__ ch,              // (B,128)
    const float* __restrict__ b_pos,           // (2)
    const unsigned short* __restrict__ wposA,  // (16,128) bf16
    const unsigned short* __restrict__ weff,   // (512,128) bf16
    const float* __restrict__ beff,            // (512)
    const float* __restrict__ m2,              // (2,512)
    float* __restrict__ out)                   // rels (32,B,2) ++ h (B,128)
{
    __shared__ __align__(16) unsigned short lh[2][16][136];  // [buf][batch][hcol]
    __shared__ float ubuf[16][2];

    const int tid  = threadIdx.x;
    const int w    = tid >> 6;
    const int lane = tid & 63;
    const int q    = lane >> 4;
    const int l    = lane & 15;
    const int row0 = blockIdx.x << 4;
    const int batch = row0 + l;

    // resident W_eff A-frags + bias float4s (bias used directly as MFMA C)
    bf16_8 wA[8][4];
    float4v bias4[8];
#pragma unroll
    for (int t8 = 0; t8 < 8; ++t8){
        int nbase = ((t8 >> 1) << 7) + 32*w + ((t8 & 1) << 4);
        int gA = nbase + l;                    // A-frag row (gate) for this lane
#pragma unroll
        for (int kt = 0; kt < 4; ++kt)
            wA[t8][kt] = *(const bf16_8*)(weff + (gA << 7) + kt*32 + (q << 3));
        bias4[t8] = *(const float4v*)(beff + nbase + (q << 2));
    }

    // w_pos A-frags (all waves; rel duty rotates)
    bf16_8 wpA[4];
#pragma unroll
    for (int kt = 0; kt < 4; ++kt)
        wpA[kt] = *(const bf16_8*)(wposA + (l << 7) + kt*32 + (q << 3));
    const float bp0 = b_pos[0], bp1 = b_pos[1];

    // c state: fp32 straight from global (no quantization)
    float4v cst[2];
#pragma unroll
    for (int X = 0; X < 2; ++X)
        cst[X] = *(const float4v*)(ch + (batch << 7) + 32*w + 16*X + (q << 2));

    // h0 B-frags straight from global (fp32 -> bf16)
    bf16_8 b[4];
#pragma unroll
    for (int kt = 0; kt < 4; ++kt){
        const float* ph = hh + (batch << 7) + kt*32 + (q << 3);
        float4v h0 = *(const float4v*)ph;
        float4v h1 = *(const float4v*)(ph + 4);
        bf16_8 t;
        t[0]=(__bf16)h0[0]; t[1]=(__bf16)h0[1]; t[2]=(__bf16)h0[2]; t[3]=(__bf16)h0[3];
        t[4]=(__bf16)h1[0]; t[5]=(__bf16)h1[1]; t[6]=(__bf16)h1[2]; t[7]=(__bf16)h1[3];
        b[kt] = t;
    }

    // wave0: r_{-1} = w_pos·h0 + b_pos ; u0' = lpr - r_{-1}
    if (w == 0){
        float4v r = {0.f, 0.f, 0.f, 0.f};
#pragma unroll
        for (int kt = 0; kt < 4; ++kt)
            r = __builtin_amdgcn_mfma_f32_16x16x32_bf16(wpA[kt], b[kt], r, 0, 0, 0);
        if (q == 0){
            float2v lp = *(const float2v*)(lpr + (batch << 1));
            ubuf[l][0] = lp[0] - (r[0] + bp0);
            ubuf[l][1] = lp[1] - (r[1] + bp1);
        }
    }
    __syncthreads();

    float4v acc[8];

    auto do_gates = [&](){
#pragma unroll
        for (int t8 = 0; t8 < 8; ++t8)     // kt=0 consumes bias as C: free init
            acc[t8] = __builtin_amdgcn_mfma_f32_16x16x32_bf16(wA[t8][0], b[0], bias4[t8], 0, 0, 0);
#pragma unroll
        for (int kt = 1; kt < 4; ++kt)
#pragma unroll
            for (int t8 = 0; t8 < 8; ++t8)
                acc[t8] = __builtin_amdgcn_mfma_f32_16x16x32_bf16(wA[t8][kt], b[kt], acc[t8], 0, 0, 0);
    };

    auto do_elem_write = [&](int buf, bool finalh){
#pragma unroll
        for (int X = 0; X < 2; ++X){
            bf16_4 hv;
            float4v hf;
#pragma unroll
            for (int r4 = 0; r4 < 4; ++r4){
                float ig = acc[0 + X][r4];
                float fg = acc[2 + X][r4];
                float gg = acc[4 + X][r4];
                float og = acc[6 + X][r4];
                float c2 = fsig(fg)*cst[X][r4] + fsig(ig)*ftanh(gg);
                float h2 = fsig(og)*ftanh(c2);
                cst[X][r4] = c2;
                hv[r4] = (__bf16)h2;
                hf[r4] = h2;
            }
            *(bf16_4*)&lh[buf][l][32*w + 16*X + (q << 2)] = hv;   // packed b64
            if (finalh)
                *(float4v*)(out + SEQ*B_TOT*2 + (batch << 7) + 32*w + 16*X + (q << 2)) = hf;
        }
    };

    auto reload_and_rel = [&](int buf, int t){
#pragma unroll
        for (int kt = 0; kt < 4; ++kt)
            b[kt] = *(const bf16_8*)&lh[buf][l][kt*32 + (q << 3)];
        if (w == (t & 3)){                    // rotate rel duty across waves
            float4v r = {0.f, 0.f, 0.f, 0.f};
#pragma unroll
            for (int kt = 0; kt < 4; ++kt)
                r = __builtin_amdgcn_mfma_f32_16x16x32_bf16(wpA[kt], b[kt], r, 0, 0, 0);
            if (q == 0){
                float2v rv;
                rv[0] = r[0] + bp0;
                rv[1] = r[1] + bp1;
                *(float2v*)(out + t*(B_TOT*2) + (batch << 1)) = rv;
            }
        }
    };

    // ---- step 0 (peeled: rank-2 input correction along the gate dim) ----
    do_gates();
    {
        float u0 = ubuf[l][0], u1 = ubuf[l][1];
#pragma unroll
        for (int t8 = 0; t8 < 8; ++t8){
            int g0 = ((t8 >> 1) << 7) + 32*w + ((t8 & 1) << 4) + (q << 2);
            float4v ma = *(const float4v*)(m2 + g0);
            float4v mb = *(const float4v*)(m2 + 512 + g0);
#pragma unroll
            for (int r4 = 0; r4 < 4; ++r4)
                acc[t8][r4] += u0*ma[r4] + u1*mb[r4];
        }
    }
    do_elem_write(1, false);
    __syncthreads();
    reload_and_rel(1, 0);

    // ---- steps 1..31 ----
    for (int t = 1; t < SEQ; ++t){
        do_gates();
        do_elem_write((t + 1) & 1, t == SEQ - 1);
        __syncthreads();
        reload_and_rel((t + 1) & 1, t);
    }
}

extern "C" void kernel_launch(void* const* d_in, const int* in_sizes, int n_in,
                              void* d_out, int out_size, void* d_ws, size_t ws_size,
                              hipStream_t stream)
{
    (void)in_sizes; (void)n_in; (void)out_size; (void)ws_size;

    const float* lpr   = (const float*)d_in[1];
    const float* hh    = (const float*)d_in[2];
    const float* ch    = (const float*)d_in[3];
    const float* w_ih  = (const float*)d_in[5];
    const float* w_hh  = (const float*)d_in[6];
    const float* b_ih  = (const float*)d_in[7];
    const float* b_hh  = (const float*)d_in[8];
    const float* w_emb = (const float*)d_in[9];
    const float* b_emb = (const float*)d_in[10];
    const float* w_pos = (const float*)d_in[11];
    const float* b_pos = (const float*)d_in[12];

    unsigned short* weff  = (unsigned short*)d_ws;                     // 512*128 bf16
    float* beff           = (float*)((char*)d_ws + 131072);            // 512 f32
    float* m2             = (float*)((char*)d_ws + 131072 + 2048);     // 1024 f32
    unsigned short* wposA = (unsigned short*)((char*)d_ws + 131072 + 2048 + 4096); // 16*128 bf16

    hipLaunchKernelGGL(prep_kernel, dim3(1), dim3(512), 0, stream,
                       w_ih, w_hh, b_ih, b_hh, w_emb, b_emb, w_pos, b_pos,
                       weff, beff, m2, wposA);
    hipLaunchKernelGGL(dec_kernel, dim3(B_TOT/16), dim3(256), 0, stream,
                       lpr, hh, ch, b_pos, wposA, weff, beff, m2,
                       (float*)d_out);
}

// Round 4
// 497.333 us; speedup vs baseline: 1.1042x; 1.0968x over previous
//
#include <hip/hip_runtime.h>

#define B_TOT 65536
#define SEQ   32

typedef __bf16 bf16_8 __attribute__((ext_vector_type(8)));
typedef __bf16 bf16_4 __attribute__((ext_vector_type(4)));
typedef float  float4v __attribute__((ext_vector_type(4)));
typedef float  float2v __attribute__((ext_vector_type(2)));

#define SC1 (-1.4426950408889634f)   // -log2(e): i,f,o gate rows
#define SC2 (-2.8853900817779268f)   // -2*log2(e): g gate rows (and tanh(c2))

__device__ inline unsigned short f2bf(float f){
    unsigned u = __builtin_bit_cast(unsigned, f);
    u += 0x7FFFu + ((u >> 16) & 1u);           // round-to-nearest-even
    return (unsigned short)(u >> 16);
}

// ---- prep: W_eff = w_hh.T + w_pos.T @ (w_emb.T @ w_ih.T); biases folded;
// rows pre-scaled by -log2e (i,f,o) / -2log2e (g) so exp2 needs no mul. ----
__global__ void prep_kernel(const float* __restrict__ w_ih,
                            const float* __restrict__ w_hh,
                            const float* __restrict__ b_ih,
                            const float* __restrict__ b_hh,
                            const float* __restrict__ w_emb,
                            const float* __restrict__ b_emb,
                            const float* __restrict__ w_pos,
                            const float* __restrict__ b_pos,
                            unsigned short* __restrict__ weff,
                            float* __restrict__ beff,
                            float* __restrict__ m2,
                            unsigned short* __restrict__ wposA)
{
    int n = threadIdx.x;                       // 512 threads, one gate row each
    float m20 = 0.f, m21 = 0.f, bi = 0.f;
    for (int e = 0; e < 64; ++e){
        float wv = w_ih[n*64 + e];
        m20 += w_emb[e*2 + 0] * wv;
        m21 += w_emb[e*2 + 1] * wv;
        bi  += b_emb[e] * wv;
    }
    float sc = ((n >> 7) == 2) ? SC2 : SC1;    // gate order [i,f,g,o]
    m2[n]       = m20 * sc;
    m2[512 + n] = m21 * sc;
    beff[n] = (b_ih[n] + b_hh[n] + bi + b_pos[0]*m20 + b_pos[1]*m21) * sc;
    for (int k = 0; k < 128; ++k){
        float wv = w_hh[n*128 + k] + w_pos[k]*m20 + w_pos[128 + k]*m21;
        weff[n*128 + k] = f2bf(wv * sc);
    }
    if (n < 256) wposA[n] = f2bf(w_pos[n]);    // unscaled: rel path
    for (int idx = n; idx < 14*128; idx += 512) wposA[256 + idx] = 0;
}

// ---- main decoder: G^T = W_eff(A) x h^T(B); 16 rows/block, 4 waves ----
__global__ __launch_bounds__(256, 2) void dec_kernel(
    const float* __restrict__ lpr,             // (B,2)
    const float* __restrict__ hh,              // (B,128)
    const float* __restrict__ ch,              // (B,128)
    const float* __restrict__ b_pos,           // (2)
    const unsigned short* __restrict__ wposA,  // (16,128) bf16
    const unsigned short* __restrict__ weff,   // (512,128) bf16 pre-scaled
    const float* __restrict__ beff,            // (512) pre-scaled
    const float* __restrict__ m2,              // (2,512) pre-scaled
    float* __restrict__ out)                   // rels (32,B,2) ++ h (B,128)
{
    __shared__ __align__(16) unsigned short lh[2][16][136];  // [buf][batch][hcol]
    __shared__ float ubuf[16][2];
    __shared__ __align__(16) float hsh[16][128];             // final-h staging

    const int tid  = threadIdx.x;
    const int w    = tid >> 6;
    const int lane = tid & 63;
    const int q    = lane >> 4;
    const int l    = lane & 15;
    const int row0 = blockIdx.x << 4;
    const int batch = row0 + l;

    // resident W_eff A-frags + bias float4s (bias used directly as MFMA C)
    bf16_8 wA[8][4];
    float4v bias4[8];
#pragma unroll
    for (int t8 = 0; t8 < 8; ++t8){
        int nbase = ((t8 >> 1) << 7) + 32*w + ((t8 & 1) << 4);
        int gA = nbase + l;
#pragma unroll
        for (int kt = 0; kt < 4; ++kt)
            wA[t8][kt] = *(const bf16_8*)(weff + (gA << 7) + kt*32 + (q << 3));
        bias4[t8] = *(const float4v*)(beff + nbase + (q << 2));
    }

    // w_pos A-frags (all waves; rel duty rotates)
    bf16_8 wpA[4];
#pragma unroll
    for (int kt = 0; kt < 4; ++kt)
        wpA[kt] = *(const bf16_8*)(wposA + (l << 7) + kt*32 + (q << 3));
    const float bp0 = b_pos[0], bp1 = b_pos[1];

    // c state: fp32 straight from global
    float4v cst[2];
#pragma unroll
    for (int X = 0; X < 2; ++X)
        cst[X] = *(const float4v*)(ch + (batch << 7) + 32*w + 16*X + (q << 2));

    // h0 B-frags straight from global (fp32 -> bf16)
    bf16_8 b[4];
#pragma unroll
    for (int kt = 0; kt < 4; ++kt){
        const float* ph = hh + (batch << 7) + kt*32 + (q << 3);
        float4v h0 = *(const float4v*)ph;
        float4v h1 = *(const float4v*)(ph + 4);
        bf16_8 t;
        t[0]=(__bf16)h0[0]; t[1]=(__bf16)h0[1]; t[2]=(__bf16)h0[2]; t[3]=(__bf16)h0[3];
        t[4]=(__bf16)h1[0]; t[5]=(__bf16)h1[1]; t[6]=(__bf16)h1[2]; t[7]=(__bf16)h1[3];
        b[kt] = t;
    }

    // wave0: r_{-1} = w_pos·h0 + b_pos ; u0' = lpr - r_{-1}
    if (w == 0){
        float4v r = {0.f, 0.f, 0.f, 0.f};
#pragma unroll
        for (int kt = 0; kt < 4; ++kt)
            r = __builtin_amdgcn_mfma_f32_16x16x32_bf16(wpA[kt], b[kt], r, 0, 0, 0);
        if (q == 0){
            float2v lp = *(const float2v*)(lpr + (batch << 1));
            ubuf[l][0] = lp[0] - (r[0] + bp0);
            ubuf[l][1] = lp[1] - (r[1] + bp1);
        }
    }
    __syncthreads();

    float4v acc[8];

    auto do_gates = [&](){
#pragma unroll
        for (int t8 = 0; t8 < 8; ++t8)     // kt=0 consumes bias as C: free init
            acc[t8] = __builtin_amdgcn_mfma_f32_16x16x32_bf16(wA[t8][0], b[0], bias4[t8], 0, 0, 0);
#pragma unroll
        for (int kt = 1; kt < 4; ++kt)
#pragma unroll
            for (int t8 = 0; t8 < 8; ++t8)
                acc[t8] = __builtin_amdgcn_mfma_f32_16x16x32_bf16(wA[t8][kt], b[kt], acc[t8], 0, 0, 0);
    };

    // merged-reciprocal LSTM cell: 5 exp2 + 2 rcp per element
    auto do_elem_write = [&](int buf, bool finalh){
#pragma unroll
        for (int X = 0; X < 2; ++X){
            bf16_4 hv;
#pragma unroll
            for (int r4 = 0; r4 < 4; ++r4){
                float ei = __builtin_amdgcn_exp2f(acc[0 + X][r4]);  // e^{-i}
                float ef = __builtin_amdgcn_exp2f(acc[2 + X][r4]);  // e^{-f}
                float eg = __builtin_amdgcn_exp2f(acc[4 + X][r4]);  // e^{-2g}
                float pi_ = 1.f + ei, pf = 1.f + ef;
                float pg  = 1.f + eg, mg = 1.f - eg;
                float t2  = pi_ * pg;
                float den = pf * t2;
                float num = fmaf(cst[X][r4], t2, pf * mg);
                float c2  = num * __builtin_amdgcn_rcpf(den);
                float eo  = __builtin_amdgcn_exp2f(acc[6 + X][r4]); // e^{-o}
                float ec  = __builtin_amdgcn_exp2f(c2 * SC2);       // e^{-2c2}
                float po = 1.f + eo, pc = 1.f + ec, mc = 1.f - ec;
                float h2 = mc * __builtin_amdgcn_rcpf(po * pc);
                cst[X][r4] = c2;
                hv[r4] = (__bf16)h2;
                if (finalh) hsh[l][32*w + 16*X + (q << 2) + r4] = h2;
            }
            *(bf16_4*)&lh[buf][l][32*w + 16*X + (q << 2)] = hv;   // packed b64
        }
    };

    auto reload_and_rel = [&](int buf, int t){
#pragma unroll
        for (int kt = 0; kt < 4; ++kt)
            b[kt] = *(const bf16_8*)&lh[buf][l][kt*32 + (q << 3)];
        if (w == (t & 3)){                    // rotate rel duty across waves
            float4v r = {0.f, 0.f, 0.f, 0.f};
#pragma unroll
            for (int kt = 0; kt < 4; ++kt)
                r = __builtin_amdgcn_mfma_f32_16x16x32_bf16(wpA[kt], b[kt], r, 0, 0, 0);
            if (q == 0){
                float2v rv;
                rv[0] = r[0] + bp0;
                rv[1] = r[1] + bp1;
                *(float2v*)(out + t*(B_TOT*2) + (batch << 1)) = rv;
            }
        }
    };

    // ---- step 0 (peeled: rank-2 input correction along the gate dim) ----
    do_gates();
    {
        float u0 = ubuf[l][0], u1 = ubuf[l][1];
#pragma unroll
        for (int t8 = 0; t8 < 8; ++t8){
            int g0 = ((t8 >> 1) << 7) + 32*w + ((t8 & 1) << 4) + (q << 2);
            float4v ma = *(const float4v*)(m2 + g0);
            float4v mb = *(const float4v*)(m2 + 512 + g0);
#pragma unroll
            for (int r4 = 0; r4 < 4; ++r4)
                acc[t8][r4] += u0*ma[r4] + u1*mb[r4];
        }
    }
    do_elem_write(1, false);
    __syncthreads();
    reload_and_rel(1, 0);

    // ---- steps 1..31 ----
    for (int t = 1; t < SEQ; ++t){
        do_gates();
        do_elem_write((t + 1) & 1, t == SEQ - 1);
        __syncthreads();
        reload_and_rel((t + 1) & 1, t);
    }

    // ---- coalesced final-h store: LDS-staged, contiguous 32 B per thread ----
    __syncthreads();
    {
        int r = tid >> 4, c8 = (tid & 15) << 3;
        float4v v0 = *(const float4v*)&hsh[r][c8];
        float4v v1 = *(const float4v*)&hsh[r][c8 + 4];
        float* po = out + SEQ*B_TOT*2 + ((row0 + r) << 7) + c8;
        *(float4v*)po = v0;
        *(float4v*)(po + 4) = v1;
    }
}

extern "C" void kernel_launch(void* const* d_in, const int* in_sizes, int n_in,
                              void* d_out, int out_size, void* d_ws, size_t ws_size,
                              hipStream_t stream)
{
    (void)in_sizes; (void)n_in; (void)out_size; (void)ws_size;

    const float* lpr   = (const float*)d_in[1];
    const float* hh    = (const float*)d_in[2];
    const float* ch    = (const float*)d_in[3];
    const float* w_ih  = (const float*)d_in[5];
    const float* w_hh  = (const float*)d_in[6];
    const float* b_ih  = (const float*)d_in[7];
    const float* b_hh  = (const float*)d_in[8];
    const float* w_emb = (const float*)d_in[9];
    const float* b_emb = (const float*)d_in[10];
    const float* w_pos = (const float*)d_in[11];
    const float* b_pos = (const float*)d_in[12];

    unsigned short* weff  = (unsigned short*)d_ws;                     // 512*128 bf16
    float* beff           = (float*)((char*)d_ws + 131072);            // 512 f32
    float* m2             = (float*)((char*)d_ws + 131072 + 2048);     // 1024 f32
    unsigned short* wposA = (unsigned short*)((char*)d_ws + 131072 + 2048 + 4096); // 16*128 bf16

    hipLaunchKernelGGL(prep_kernel, dim3(1), dim3(512), 0, stream,
                       w_ih, w_hh, b_ih, b_hh, w_emb, b_emb, w_pos, b_pos,
                       weff, beff, m2, wposA);
    hipLaunchKernelGGL(dec_kernel, dim3(B_TOT/16), dim3(256), 0, stream,
                       lpr, hh, ch, b_pos, wposA, weff, beff, m2,
                       (float*)d_out);
}